// Round 5
// baseline (1733.184 us; speedup 1.0000x reference)
//
#include <hip/hip_runtime.h>
#include <hip/hip_fp16.h>

#define BATCH 1024
#define SEQ   64
#define HID   128
#define TOUT  24
#define EPS   132   // ep16 row stride (halfs)

typedef unsigned int u32;
typedef _Float16 f16;
typedef __attribute__((ext_vector_type(8))) f16 f16x8;
typedef __attribute__((ext_vector_type(4))) float f32x4;

static __device__ __forceinline__ float sigm(float x){
  return __builtin_amdgcn_rcpf(1.f + __expf(-x));
}
static __device__ __forceinline__ float tanh_fast(float x){
  return fmaf(2.f, __builtin_amdgcn_rcpf(1.f + __expf(-2.f*x)), -1.f);
}
// half-index of element (row m<4, k<128) inside ONE 2048-half A-fragment half-tile.
// lane = m + ((k>>3)&3)*16, slot j = k&7, ktile = k>>5  -> conflict-free b128 reads.
static __device__ __forceinline__ int slotk(int r, int k){
  return ((k>>5)*64 + r + ((k>>3)&3)*16)*8 + (k&7);
}

// ---- GEMM with register-resident weights: D[16x512] = A[16xK] * B[Kx512]
template<int KT>
static __device__ __forceinline__ void mfma_gates_reg(const f16x8* Bf,
    const __half* __restrict__ A0, const __half* __restrict__ A1,
    float* __restrict__ gpre, int lane, int w)
{
  f16x8 a[KT];
#pragma unroll
  for (int kt=0; kt<KT; ++kt){
    const __half* src = (kt<4) ? (A0 + (kt*64+lane)*8) : (A1 + ((kt-4)*64+lane)*8);
    a[kt] = *(const f16x8*)src;
  }
#pragma unroll
  for (int nt=0; nt<4; ++nt){
    f32x4 acc = {0.f,0.f,0.f,0.f};
#pragma unroll
    for (int kt=0; kt<KT; ++kt)
      acc = __builtin_amdgcn_mfma_f32_16x16x32_f16(a[kt], Bf[nt*KT+kt], acc, 0,0,0);
    if (lane < 16){
      int col = (w*4+nt)*16 + lane;
#pragma unroll
      for (int q=0; q<4; ++q) gpre[q*512 + col] = acc[q];
    }
  }
}

template<int NF>
static __device__ __forceinline__ void load_wslice(const __half* __restrict__ W,
    f16x8* Bf, int lane, int w)
{
  const f16x8* wb = (const f16x8*)W + (size_t)(w*NF)*64 + lane;
#pragma unroll
  for (int i=0; i<NF; ++i) Bf[i] = wb[(size_t)i*64];
}

// ---- streamed GEMM (decoder): K=256; full 32-frag queue, pinned, then compute
static __device__ __forceinline__ void mfma_gates_stream(const __half* __restrict__ W,
    const __half* __restrict__ A, float* __restrict__ gpre, int lane, int w)
{
  const f16x8* wb = (const f16x8*)W + (size_t)(w*32)*64 + lane;
  f16x8 q[32];
#pragma unroll
  for (int i=0; i<32; ++i) q[i] = wb[(size_t)i*64];
  f16x8 a[8];
#pragma unroll
  for (int kt=0; kt<8; ++kt) a[kt] = *(const f16x8*)(A + (kt*64+lane)*8);
#pragma unroll
  for (int i=0; i<32; ++i) asm volatile("" : "+v"(q[i]));
#pragma unroll
  for (int nt=0; nt<4; ++nt){
    f32x4 acc = {0.f,0.f,0.f,0.f};
#pragma unroll
    for (int kt=0; kt<8; ++kt)
      acc = __builtin_amdgcn_mfma_f32_16x16x32_f16(a[kt], q[nt*8+kt], acc, 0,0,0);
    if (lane < 16){
      int col = (w*4+nt)*16 + lane;
#pragma unroll
      for (int qq=0; qq<4; ++qq) gpre[qq*512 + col] = acc[qq];
    }
  }
}

// ---------------- weight prep: fp32 -> MFMA B-fragment fp16 layouts ----------------
// B-frag: element (col = nt*16 + (l&15), k = kt*32 + (l>>4)*8 + j) at [nt][kt][l][j]
__global__ void prep_kernel(
    const float* __restrict__ eWih0,  const float* __restrict__ eWhh0,
    const float* __restrict__ eWih12, const float* __restrict__ eWhh12,
    const float* __restrict__ aW,
    const float* __restrict__ dWih0,  const float* __restrict__ dWhh0,
    const float* __restrict__ dWih12, const float* __restrict__ dWhh12,
    const float* __restrict__ oW,
    __half* __restrict__ wE0, __half* __restrict__ wE1, __half* __restrict__ wE2,
    __half* __restrict__ wD0, __half* __restrict__ wD1, __half* __restrict__ wD2,
    __half* __restrict__ wAh, float* __restrict__ wAe, float* __restrict__ wOT,
    float* __restrict__ dW2)
{
  int id = blockIdx.x*blockDim.x + threadIdx.x;
  if (id < 65536){                                   // wE0: K=128 (h only), KT=4
    int m=id, j=m&7, l=(m>>3)&63, kt=(m>>9)&3, nt=m>>11;
    int col = nt*16 + (l&15), k = kt*32 + ((l>>4)<<3) + j;
    wE0[m] = __float2half(eWhh0[col*128 + k]); return;
  }
  id -= 65536;
  if (id < 5*131072){                                // wE1,wE2,wD0,wD1,wD2: K=256, KT=8
    int seg = id >> 17, m = id & 131071;
    int j=m&7, l=(m>>3)&63, kt=(m>>9)&7, nt=m>>12;
    int col = nt*16 + (l&15), k = kt*32 + ((l>>4)<<3) + j;
    float v;
    if (seg==0)      v = (k<128)? eWih12[col*128+k]         : eWhh12[col*128 + (k-128)];
    else if (seg==1) v = (k<128)? eWih12[65536+col*128+k]   : eWhh12[65536 + col*128 + (k-128)];
    else if (seg==2) v = (k<128)? dWih0[col*130 + 2 + k]    : dWhh0[col*128 + (k-128)];
    else if (seg==3) v = (k<128)? dWih12[col*128+k]         : dWhh12[col*128 + (k-128)];
    else             v = (k<128)? dWih12[65536+col*128+k]   : dWhh12[65536 + col*128 + (k-128)];
    __half* dst = (seg==0)?wE1:(seg==1)?wE2:(seg==2)?wD0:(seg==3)?wD1:wD2;
    dst[m] = __float2half(v); return;
  }
  id -= 5*131072;
  if (id < 16384){                                   // wAh: attn_W[:, :H], K=128, 8 nt x 4 kt
    int m=id, j=m&7, l=(m>>3)&63, kt=(m>>9)&3, nt=m>>11;
    int col = nt*16 + (l&15), k = kt*32 + ((l>>4)<<3) + j;
    wAh[m] = __float2half(aW[col*256 + k]); return;
  }
  id -= 16384;
  if (id < 16384){ int k=id>>7, jq=id&127; wAe[id] = aW[jq*256 + 128 + k]; return; }  // [k][j] f32
  id -= 16384;
  if (id < 512){ int k=id>>1, jo=id&1; wOT[id] = oW[jo*256 + k]; return; }            // [k][2] f32
  id -= 512;
  if (id < 1024){ int col=id>>1, ki=id&1; dW2[id] = dWih0[col*130 + ki]; return; }    // [n][2] f32
}

// ---------------- main persistent kernel: 256 blocks x 512 thr, 4 batch rows each ----------------
__global__ __launch_bounds__(512, 2) void seq2seq_main(
    const float* __restrict__ x, const float* __restrict__ prev_y,
    const float* __restrict__ enc_b0, const float* __restrict__ enc_b12,
    const float* __restrict__ attn_b, const float* __restrict__ vW,
    const float* __restrict__ dec_b0, const float* __restrict__ dec_b12,
    const float* __restrict__ out_b, const float* __restrict__ eWih0,
    __half* __restrict__ hsA, __half* __restrict__ hsB,
    const __half* __restrict__ wE0, const __half* __restrict__ wE1, const __half* __restrict__ wE2,
    const __half* __restrict__ wD0, const __half* __restrict__ wD1, const __half* __restrict__ wD2,
    const __half* __restrict__ wAh, const float* __restrict__ wAe, const float* __restrict__ wOT,
    const float* __restrict__ dW2, float* __restrict__ dout)
{
  // Afrag half-tiles (2048 halfs each): ht0 = input/weighted, ht1 = h0, ht2 = h1, ht3 = h2
  __shared__ __align__(16) __half Afrag[4*2048];
  __shared__ __align__(16) float gpre[4*512];
  __shared__ __align__(16) float hw[4*256];          // [r][h2(128)|weighted(128)]
  __shared__ __align__(16) float cst[3][512];
  __shared__ float scb[4][64];
  __shared__ float xc[2][4][2];
  __shared__ float po[4][2];
  __shared__ float vwl[128];
  extern __shared__ __align__(16) __half dynLds[];
  __half* ep16 = dynLds;                             // [256][EPS]
  __half* wAhL = dynLds + 256*EPS;                   // [16384]

  const int tid  = threadIdx.x;
  const int w    = tid >> 6;
  const int lane = tid & 63;
  const int rr   = tid >> 6;      // row for tid<256 phases
  const int cr   = tid >> 7;      // row for 512-thread pointwise
  const int cj   = tid & 127;     // col for 512-thread pointwise
  const int b4   = blockIdx.x * 4;

  // pointwise LSTM cell, ONE column (cr, cj) per thread across all 8 waves
  auto cellpw = [&](const float* __restrict__ bias, float* __restrict__ crow,
                    const float* __restrict__ foldW, const float* __restrict__ fv,
                    __half* hdest, __half* hsd, float* hwd){
    const float* gpr = gpre + cr*512 + cj;
    float gi = gpr[0]   + bias[cj];
    float gf = gpr[128] + bias[cj+128];
    float gg = gpr[256] + bias[cj+256];
    float go = gpr[384] + bias[cj+384];
    if (foldW){                                      // rank-2 input fold, [512][2] rows
      float a0=fv[0], a1=fv[1];
      float2 f0 = *(const float2*)(foldW + (0*128+cj)*2);
      float2 f1 = *(const float2*)(foldW + (1*128+cj)*2);
      float2 f2 = *(const float2*)(foldW + (2*128+cj)*2);
      float2 f3 = *(const float2*)(foldW + (3*128+cj)*2);
      gi += a0*f0.x + a1*f0.y;
      gf += a0*f1.x + a1*f1.y;
      gg += a0*f2.x + a1*f2.y;
      go += a0*f3.x + a1*f3.y;
    }
    float c  = crow[cj];
    float cn = fmaf(sigm(gf), c, sigm(gi)*tanh_fast(gg));
    float hn = sigm(go)*tanh_fast(cn);
    crow[cj] = cn;
    __half hh = __float2half(hn);
    hdest[slotk(cr, cj)] = hh;
    if (hsd) *hsd = hh;
    if (hwd) hwd[cj] = hn;
  };

  // ================= encoder: 3 LSTM layers, weights register-resident =================
  const __half* Wenc[3] = {wE0, wE1, wE2};
  const float*  Benc[3] = {enc_b0, enc_b12, enc_b12 + 512};
  const __half* hsIn[3] = {nullptr, hsA, hsB};
  __half* hsOut[3]      = {hsA, hsB, hsA};   // layer2 overwrites hsA (layer0 data dead)

  f16x8 Bf[32];
  for (int layer=0; layer<3; ++layer){
    if (layer==0){
      load_wslice<16>(wE0, Bf, lane, w);
#pragma unroll
      for (int i=0;i<16;++i) asm volatile("" : "+v"(Bf[i]));
    } else {
      load_wslice<32>(Wenc[layer], Bf, lane, w);
#pragma unroll
      for (int i=0;i<32;++i) asm volatile("" : "+v"(Bf[i]));
    }
    __half* hbuf = Afrag + (1+layer)*2048;
    if (tid < 256){
      *(u32*)(hbuf + slotk(rr, 2*lane)) = 0u;                  // h = 0
      *(float2*)(&cst[layer][rr*128 + 2*lane]) = make_float2(0.f, 0.f);
      if (layer==0){
        if (tid < 8){ int r=tid>>1, xi=tid&1; xc[0][r][xi] = x[((size_t)(b4+r)*SEQ + 0)*2 + xi]; }
      } else {
        int r = rr, dp = lane;
        u32 hv = *((const u32*)hsIn[layer] + ((size_t)(b4+r)*SEQ + 0)*64 + dp);
        *(u32*)(Afrag + slotk(r, 2*dp)) = hv;
      }
    }
    __syncthreads();
    for (int t=0; t<SEQ; ++t){
      if (layer==0) mfma_gates_reg<4>(Bf, hbuf,  hbuf, gpre, lane, w);
      else          mfma_gates_reg<8>(Bf, Afrag, hbuf, gpre, lane, w);
      __syncthreads();
      u32 hv = 0u;
      if (t+1 < SEQ){
        if (layer==0){
          if (tid < 8){ int r=tid>>1, xi=tid&1; xc[(t+1)&1][r][xi] = x[((size_t)(b4+r)*SEQ + t+1)*2 + xi]; }
        } else if (tid < 256){
          hv = *((const u32*)hsIn[layer] + ((size_t)(b4+rr)*SEQ + t+1)*64 + lane);
        }
      }
      __half* hsd = hsOut[layer] + ((size_t)(b4+cr)*SEQ + t)*HID + cj;
      cellpw(Benc[layer], &cst[layer][cr*128],
             (layer==0)? eWih0 : nullptr, xc[t&1][cr], hbuf, hsd, nullptr);
      if (t+1 < SEQ && layer>0 && tid < 256)
        *(u32*)(Afrag + slotk(rr, 2*lane)) = hv;
      __syncthreads();
    }
  }
  __syncthreads();

  // ================= enc-side attention projection (once) =================
  {
    int rs = tid>>1, r = rs>>6, s = rs&63, jh = tid&1;
    const u32* arow = (const u32*)hsA + ((size_t)(b4+r)*SEQ + s)*64;
    u32 a[64];
#pragma unroll
    for (int i=0;i<16;++i){
      uint4 v = ((const uint4*)arow)[i];
      a[4*i]=v.x; a[4*i+1]=v.y; a[4*i+2]=v.z; a[4*i+3]=v.w;
    }
    float acc[64];
    const float* ab = attn_b + jh*64;
#pragma unroll
    for (int jq=0;jq<64;++jq) acc[jq] = ab[jq];
    for (int kp=0; kp<64; ++kp){
      float2 af = __half22float2(*(const __half2*)&a[kp]);
      const float* w0 = wAe + (size_t)(2*kp)*HID + jh*64;
      const float* w1 = w0 + HID;
#pragma unroll
      for (int jq=0;jq<64;++jq) acc[jq] = fmaf(af.x, w0[jq], acc[jq]);
#pragma unroll
      for (int jq=0;jq<64;++jq) acc[jq] = fmaf(af.y, w1[jq], acc[jq]);
    }
    __half2* ep = (__half2*)(ep16 + (size_t)rs*EPS + jh*64);
#pragma unroll
    for (int p=0;p<32;++p) ep[p] = __floats2half2_rn(acc[2*p], acc[2*p+1]);
  }
  // decoder prologue
  if (tid < 8){ po[tid>>1][tid&1] = prev_y[(b4 + (tid>>1))*2 + (tid&1)]; }
  if (tid < 128) vwl[tid] = vW[tid];
  for (int i=tid; i<8192; i+=512) ((u32*)wAhL)[i] = ((const u32*)wAh)[i];
  __syncthreads();

  // ================= decoder: 24 autoregressive steps =================
  for (int t=0; t<TOUT; ++t){
    {  // hproj = h2 @ attn_Wh (B from LDS); wave w owns ntile w of 8
      f16x8 a[4], bw[4];
#pragma unroll
      for (int kt=0;kt<4;++kt) a[kt]  = *(const f16x8*)(Afrag + 3*2048 + (kt*64+lane)*8);
#pragma unroll
      for (int kt=0;kt<4;++kt) bw[kt] = *(const f16x8*)(wAhL + ((w*4+kt)*64+lane)*8);
      f32x4 acc = {0.f,0.f,0.f,0.f};
#pragma unroll
      for (int kt=0;kt<4;++kt)
        acc = __builtin_amdgcn_mfma_f32_16x16x32_f16(a[kt], bw[kt], acc, 0,0,0);
      if (lane < 16){
        int col = w*16 + lane;
#pragma unroll
        for (int q=0;q<4;++q) gpre[q*512+col] = acc[q];
      }
    }
    __syncthreads();
    {  // scores: thread (rs, jh)
      int rs = tid>>1, r = rs>>6, s = rs&63, jh = tid&1;
      const __half2* ep = (const __half2*)(ep16 + (size_t)rs*EPS + jh*64);
      const float* hp = gpre + r*512 + jh*64;
      float s_ = 0.f;
#pragma unroll
      for (int i=0;i<32;++i){
        float2 e = __half22float2(ep[i]);
        s_ = fmaf(tanh_fast(e.x + hp[2*i]),   vwl[jh*64 + 2*i],   s_);
        s_ = fmaf(tanh_fast(e.y + hp[2*i+1]), vwl[jh*64 + 2*i+1], s_);
      }
      s_ += __shfl_xor(s_, 1);
      if (jh==0) scb[r][s] = s_;
    }
    __syncthreads();
    if (tid < 256){   // softmax + weighted -> ht0 + hw
      float sv = scb[rr][lane];
      float mx = sv;
#pragma unroll
      for (int off=32; off; off>>=1) mx = fmaxf(mx, __shfl_xor(mx, off));
      float ev = __expf(sv - mx);
      float sm = ev;
#pragma unroll
      for (int off=32; off; off>>=1) sm += __shfl_xor(sm, off);
      scb[rr][lane] = ev / sm;
      const u32* eb = (const u32*)hsA + ((size_t)(b4+rr)*SEQ)*64 + lane;
      float a0=0.f, a1=0.f;
#pragma unroll 8
      for (int s2=0; s2<64; ++s2){
        float wgt = scb[rr][s2];
        float2 af = __half22float2(*(const __half2*)&eb[(size_t)s2*64]);
        a0 = fmaf(wgt, af.x, a0); a1 = fmaf(wgt, af.y, a1);
      }
      int j = 2*lane;
      *(__half2*)(Afrag + slotk(rr, j)) = __floats2half2_rn(a0, a1);
      *(float2*)(hw + rr*256 + 128 + j) = make_float2(a0, a1);
    }
    __syncthreads();
    mfma_gates_stream(wD0, Afrag,          gpre, lane, w);   // [weighted | h0]
    __syncthreads();
    cellpw(dec_b0, &cst[0][cr*128], dW2, po[cr], Afrag + 1*2048, nullptr, nullptr);
    __syncthreads();
    mfma_gates_stream(wD1, Afrag + 1*2048, gpre, lane, w);   // [h0 | h1]
    __syncthreads();
    cellpw(dec_b12, &cst[1][cr*128], nullptr, nullptr, Afrag + 2*2048, nullptr, nullptr);
    __syncthreads();
    mfma_gates_stream(wD2, Afrag + 2*2048, gpre, lane, w);   // [h1 | h2]
    __syncthreads();
    cellpw(dec_b12 + 512, &cst[2][cr*128], nullptr, nullptr, Afrag + 3*2048, nullptr, hw + cr*256);
    __syncthreads();
    if (tid < 256){   // output head
      float4 hv = *(const float4*)(hw + rr*256 + lane*4);
      float4 w0 = *(const float4*)(wOT + 8*lane);
      float4 w1 = *(const float4*)(wOT + 8*lane + 4);
      float o0 = hv.x*w0.x + hv.y*w0.z + hv.z*w1.x + hv.w*w1.z;
      float o1 = hv.x*w0.y + hv.y*w0.w + hv.z*w1.y + hv.w*w1.w;
#pragma unroll
      for (int off=32; off; off>>=1){ o0 += __shfl_down(o0,off); o1 += __shfl_down(o1,off); }
      if (lane==0){
        float v0 = o0 + out_b[0], v1 = o1 + out_b[1];
        size_t oi = ((size_t)t*BATCH + b4 + rr)*2;
        dout[oi] = v0; dout[oi+1] = v1;
        po[rr][0] = v0; po[rr][1] = v1;
      }
    }
    __syncthreads();
  }
}

extern "C" void kernel_launch(void* const* d_in, const int* in_sizes, int n_in,
                              void* d_out, int out_size, void* d_ws, size_t ws_size,
                              hipStream_t stream) {
  const float* x      = (const float*)d_in[0];
  const float* prev_y = (const float*)d_in[1];
  const float* eWih0  = (const float*)d_in[2];
  const float* eWhh0  = (const float*)d_in[3];
  const float* eb0    = (const float*)d_in[4];
  const float* eWih12 = (const float*)d_in[5];
  const float* eWhh12 = (const float*)d_in[6];
  const float* eb12   = (const float*)d_in[7];
  const float* aW     = (const float*)d_in[8];
  const float* ab     = (const float*)d_in[9];
  const float* vW     = (const float*)d_in[10];
  const float* dWih0  = (const float*)d_in[11];
  const float* dWhh0  = (const float*)d_in[12];
  const float* db0    = (const float*)d_in[13];
  const float* dWih12 = (const float*)d_in[14];
  const float* dWhh12 = (const float*)d_in[15];
  const float* db12   = (const float*)d_in[16];
  const float* oW     = (const float*)d_in[17];
  const float* ob     = (const float*)d_in[18];

  __half* wE0 = (__half*)d_ws;           // 65536 halfs
  __half* wE1 = wE0 + 65536;             // 131072 each
  __half* wE2 = wE1 + 131072;
  __half* wD0 = wE2 + 131072;
  __half* wD1 = wD0 + 131072;
  __half* wD2 = wD1 + 131072;
  __half* wAh = wD2 + 131072;            // 16384
  float*  wAe = (float*)(wAh + 16384);   // 16384 f32
  float*  wOT = wAe + 16384;             // 512 f32
  float*  dW2 = wOT + 512;               // 1024 f32
  __half* hsA = (__half*)(dW2 + 1024);
  __half* hsB = hsA + (size_t)BATCH*SEQ*HID;

  const int prepN = 65536 + 5*131072 + 16384 + 16384 + 512 + 1024;
  prep_kernel<<<(prepN + 255)/256, 256, 0, stream>>>(
      eWih0, eWhh0, eWih12, eWhh12, aW, dWih0, dWhh0, dWih12, dWhh12, oW,
      wE0, wE1, wE2, wD0, wD1, wD2, wAh, wAe, wOT, dW2);

  const int dynBytes = 256*EPS*2 + 16384*2;   // ep16 (67,584 B) + wAhL (32,768 B)
  hipFuncSetAttribute(reinterpret_cast<const void*>(seq2seq_main),
                      hipFuncAttributeMaxDynamicSharedMemorySize, dynBytes);

  seq2seq_main<<<256, 512, dynBytes, stream>>>(
      x, prev_y, eb0, eb12, ab, vW, db0, db12, ob, eWih0,
      hsA, hsB, wE0, wE1, wE2, wD0, wD1, wD2, wAh, wAe, wOT, dW2,
      (float*)d_out);
}